// Round 6
// baseline (1575.663 us; speedup 1.0000x reference)
//
#include <hip/hip_runtime.h>
#include <hip/hip_bf16.h>
#include <string.h>

typedef __hip_bfloat16 bf16;
typedef short v8s __attribute__((ext_vector_type(8)));
typedef float v4f __attribute__((ext_vector_type(4)));

#define H_ 128
#define P_ 6
#define K_ 4
#define NBR_CAP 48

__device__ __forceinline__ float ldf(const float* p, size_t i) { return p[i]; }
__device__ __forceinline__ float ldf(const bf16* p, size_t i) { return __bfloat162float(p[i]); }

__device__ __forceinline__ float s2f(short s) {
    unsigned int u = ((unsigned int)(unsigned short)s) << 16;
    float f; __builtin_memcpy(&f, &u, 4); return f;
}
__device__ __forceinline__ short f2s(float v) {
    bf16 h = __float2bfloat16(v);
    short s; __builtin_memcpy(&s, &h, 2); return s;
}
__device__ __forceinline__ unsigned pack2(float a0, float a1) {
    return ((unsigned)(unsigned short)f2s(a1) << 16) | (unsigned)(unsigned short)f2s(a0);
}
__device__ __forceinline__ v4f MFMA(v8s a, v8s b, v4f c) {
    return __builtin_amdgcn_mfma_f32_16x16x32_bf16(a, b, c, 0, 0, 0);
}

// ---------------- CSR build: neighbor u8 lists + degree + float rowsum ----------------
__global__ __launch_bounds__(128) void k_csr(const float* __restrict__ adj,
    unsigned char* __restrict__ nbr, int* __restrict__ deg, float* __restrict__ degf)
{
    const int gi = blockIdx.x * 128 + threadIdx.x;   // (g,i), 4096 rows
    const float* row = adj + (size_t)gi * 128;
    unsigned char* nb = nbr + (size_t)gi * NBR_CAP;
    int c = 0; float s = 0.f;
    for (int j = 0; j < 128; ++j) {
        float a = row[j];
        if (a != 0.f) { s += a; if (c < NBR_CAP) nb[c] = (unsigned char)j; ++c; }
    }
    deg[gi] = (c < NBR_CAP) ? c : NBR_CAP;
    degf[gi] = s;
}

// ---------------- transpose 15 (128x128) weights to bf16 WT[w][n][k] ----------------
// 0: in_W2 | 1+2l/2+2l: gW1/gW2 l=0..2 | 7+2l/8+2l: iW1/iW2 l=0..1 | 11+2l/12+2l: glW1/glW2
__global__ __launch_bounds__(128) void k_wt(
    const float* in_W2, const float* gW1, const float* gW2,
    const float* iW1, const float* iW2, const float* glW1, const float* glW2,
    bf16* __restrict__ dst)
{
    const int w = blockIdx.x >> 7, n = blockIdx.x & 127, k = threadIdx.x;
    const float* s;
    switch (w) {
        case 0:  s = in_W2; break;
        case 1:  s = gW1; break;           case 2:  s = gW2; break;
        case 3:  s = gW1 + 16384; break;   case 4:  s = gW2 + 16384; break;
        case 5:  s = gW1 + 32768; break;   case 6:  s = gW2 + 32768; break;
        case 7:  s = iW1; break;           case 8:  s = iW2; break;
        case 9:  s = iW1 + 16384; break;   case 10: s = iW2 + 16384; break;
        case 11: s = glW1; break;          case 12: s = glW2; break;
        case 13: s = glW1 + 16384; break;  default: s = glW2 + 16384; break;
    }
    dst[(size_t)w * 16384 + n * 128 + k] = __float2bfloat16(s[k * 128 + n]);
}

// ---------------- input embedding: t1 = relu(x * W1 + b1) ----------------
__global__ __launch_bounds__(128) void k_in_t1(const float* __restrict__ x,
    const float* __restrict__ W1, const float* __restrict__ b1, float* __restrict__ t1)
{
    int r = blockIdx.x, hd = threadIdx.x;
    t1[(size_t)r * H_ + hd] = fmaxf(fmaf(x[r], W1[hd], b1[hd]), 0.f);
}

// ---------------- generic VALU fused block (embedding + tiny tail only) ----------------
template<bool DO_MM1, bool HAS_RES>
__global__ __launch_bounds__(128) void k_block(
    const float* __restrict__ in, const float* __restrict__ res, float* __restrict__ out,
    const float* __restrict__ W1, const float* __restrict__ b1,
    const float* __restrict__ W2, const float* __restrict__ b2,
    const float* __restrict__ gam, const float* __restrict__ bet)
{
    __shared__ float sA[16][136];
    __shared__ float sB[16][136];
    __shared__ float sStat[32];
    const int hd = threadIdx.x;
    const size_t row0 = (size_t)blockIdx.x * 16;
    #pragma unroll
    for (int r = 0; r < 16; ++r) sA[r][hd] = in[(row0 + r) * H_ + hd];
    __syncthreads();
    float acc[16];
    if (DO_MM1) {
        #pragma unroll
        for (int r = 0; r < 16; ++r) acc[r] = b1[hd];
        for (int k = 0; k < H_; k += 4) {
            float w0 = W1[(k+0)*H_+hd], w1 = W1[(k+1)*H_+hd], w2 = W1[(k+2)*H_+hd], w3 = W1[(k+3)*H_+hd];
            #pragma unroll
            for (int r = 0; r < 16; ++r) {
                float4 a = *(const float4*)&sA[r][k];
                acc[r] = fmaf(a.x, w0, acc[r]); acc[r] = fmaf(a.y, w1, acc[r]);
                acc[r] = fmaf(a.z, w2, acc[r]); acc[r] = fmaf(a.w, w3, acc[r]);
            }
        }
        #pragma unroll
        for (int r = 0; r < 16; ++r) sB[r][hd] = fmaxf(acc[r], 0.f);
    } else {
        #pragma unroll
        for (int r = 0; r < 16; ++r) sB[r][hd] = sA[r][hd];
    }
    __syncthreads();
    #pragma unroll
    for (int r = 0; r < 16; ++r) acc[r] = b2[hd];
    for (int k = 0; k < H_; k += 4) {
        float w0 = W2[(k+0)*H_+hd], w1 = W2[(k+1)*H_+hd], w2 = W2[(k+2)*H_+hd], w3 = W2[(k+3)*H_+hd];
        #pragma unroll
        for (int r = 0; r < 16; ++r) {
            float4 a = *(const float4*)&sB[r][k];
            acc[r] = fmaf(a.x, w0, acc[r]); acc[r] = fmaf(a.y, w1, acc[r]);
            acc[r] = fmaf(a.z, w2, acc[r]); acc[r] = fmaf(a.w, w3, acc[r]);
        }
    }
    __syncthreads();
    #pragma unroll
    for (int r = 0; r < 16; ++r) sA[r][hd] = acc[r];
    __syncthreads();
    if (hd < 16) {
        float s = 0.f, ss = 0.f;
        for (int k = 0; k < H_; ++k) { float v = sA[hd][k]; s += v; ss += v * v; }
        float mean = s * (1.f / H_);
        float var = ss * (1.f / H_) - mean * mean;
        sStat[hd] = mean; sStat[16 + hd] = rsqrtf(var + 1e-5f);
    }
    __syncthreads();
    float gv = gam[hd], bv = bet[hd];
    #pragma unroll
    for (int r = 0; r < 16; ++r) {
        float v = fmaxf((acc[r] - sStat[r]) * sStat[16 + r] * gv + bv, 0.f);
        if (HAS_RES) v += res[(row0 + r) * H_ + hd];
        out[(row0 + r) * H_ + hd] = v;
    }
}

// ---------------- gemm + bias + relu (+ optional gathered residual from h) ----------------
template<bool GATHER, typename T>
__global__ __launch_bounds__(128) void k_gemm_relu(
    const T* __restrict__ in, const float* __restrict__ res, float* __restrict__ out,
    const float* __restrict__ W, const float* __restrict__ b)
{
    __shared__ float sA[16][136];
    const int hd = threadIdx.x;
    const size_t row0 = (size_t)blockIdx.x * 16;
    #pragma unroll
    for (int r = 0; r < 16; ++r) sA[r][hd] = ldf(in, (row0 + r) * H_ + hd);
    __syncthreads();
    float acc[16];
    #pragma unroll
    for (int r = 0; r < 16; ++r) acc[r] = b[hd];
    for (int k = 0; k < H_; k += 4) {
        float w0 = W[(k+0)*H_+hd], w1 = W[(k+1)*H_+hd], w2 = W[(k+2)*H_+hd], w3 = W[(k+3)*H_+hd];
        #pragma unroll
        for (int r = 0; r < 16; ++r) {
            float4 a = *(const float4*)&sA[r][k];
            acc[r] = fmaf(a.x, w0, acc[r]); acc[r] = fmaf(a.y, w1, acc[r]);
            acc[r] = fmaf(a.z, w2, acc[r]); acc[r] = fmaf(a.w, w3, acc[r]);
        }
    }
    #pragma unroll
    for (int r = 0; r < 16; ++r) {
        size_t rr = row0 + r;
        float v = fmaxf(acc[r], 0.f);
        if (GATHER) {
            int i = (int)(rr & 127);
            int g = (int)(rr >> 11);          // rr/(128*16)
            v += res[((size_t)(g * 128 + i)) * H_ + hd];
        }
        out[rr * H_ + hd] = v;
    }
}

// ---------------- FUSED ID PIPELINE: both ID layers + p-mean, one block/subgraph ----
// Per p-channel (independent through both layers):
//   m1 closed-form -> MLP1 -> +z1 residual -> sZ (LDS only; never HBM)
//   gather(sZ) -> MLP2 -> LN -> +sZ residual -> meanAcc (registers)
// Writes only zm (bf16 512x128x128).
__global__ __launch_bounds__(512, 4) void k_id12(
    const float* __restrict__ adj, const float* __restrict__ degf,
    const int* __restrict__ subgs, const int* __restrict__ allperm,
    const float* __restrict__ idemb,
    const unsigned char* __restrict__ nbr, const int* __restrict__ deg,
    const int* __restrict__ num_node,
    bf16* __restrict__ zm, const bf16* __restrict__ WT,
    const float* __restrict__ ib1, const float* __restrict__ ib2,
    const float* __restrict__ ig, const float* __restrict__ ibn)
{
    __shared__ __align__(16) short sZ[128][136];
    __shared__ __align__(16) short sM[128][136];
    __shared__ float sEm[4][128];
    __shared__ float sAq[128][4];
    __shared__ float sDeg[128];
    __shared__ int   sPos[128];
    __shared__ int   sPerm[24];
    __shared__ float sPar[8][128];   // 0..3: L1 b1,b2,g,bn ; 4..7: L2
    const int t = threadIdx.x;
    const int lane = t & 63, wave = t >> 6;          // 8 waves
    const int quad = lane >> 4, l16 = lane & 15;
    const int b_s = blockIdx.x, g = b_s >> 4;
    const int nn = num_node[g];
    // ---- setup ----
    if (t < 24) sPerm[t] = allperm[t];
    {   // sEm (512 f32, 1/thread)
        int row = t >> 7, col = t & 127;
        sEm[row][col] = idemb[row * 128 + col] - 1.f;
    }
    if (t < 128) {
        sDeg[t] = degf[g * 128 + t];
        int pos = -1;
        #pragma unroll
        for (int q = 0; q < 4; ++q) if (subgs[b_s * 4 + q] == t) pos = q;
        sPos[t] = pos;
    }
    {   // sAq (512 f32, 1/thread)
        int i = t >> 2, q = t & 3;
        sAq[i][q] = adj[((size_t)(g * 128 + i)) * 128 + subgs[b_s * 4 + q]];
    }
    {   // sPar (1024 f32, 2/thread): layer2 params are +128 of layer1 arrays
        int pi = t >> 7, c = t & 127;
        const float* p0 = (pi == 0) ? ib1 : (pi == 1) ? ib2 : (pi == 2) ? ig : ibn;
        sPar[pi][c] = p0[c];
        sPar[pi + 4][c] = p0[c + 128];
    }
    // gather assignment: 4 threads/node, 32 cols each
    const int gnode = t >> 2;
    const int cq = (t & 3) * 32;
    const int gcnt = deg[g * 128 + gnode];
    const unsigned char* gnb = nbr + (size_t)(g * 128 + gnode) * NBR_CAP;
    __syncthreads();

    v4f meanAcc[8];
    #pragma unroll
    for (int nt = 0; nt < 8; ++nt) meanAcc[nt] = (v4f){0.f, 0.f, 0.f, 0.f};
    const bf16* W1a = WT + (size_t)7 * 16384;
    const bf16* W2a = WT + (size_t)8 * 16384;
    const bf16* W1b = WT + (size_t)9 * 16384;
    const bf16* W2b = WT + (size_t)10 * 16384;

    for (int p = 0; p < P_; ++p) {
        // ---- m1 closed-form -> sM ----
        {
            const int c2 = (t & 63) * 2, rq = t >> 6;
            float e0[4], e1[4];
            #pragma unroll
            for (int q = 0; q < 4; ++q) {
                int e = sPerm[q * 6 + p];
                e0[q] = sEm[e][c2]; e1[q] = sEm[e][c2 + 1];
            }
            #pragma unroll
            for (int r = 0; r < 16; ++r) {
                int i = rq * 16 + r;
                float4 aq = *(const float4*)&sAq[i][0];
                float dg = sDeg[i];
                float v0 = dg, v1 = dg;
                v0 = fmaf(aq.x, e0[0], v0); v1 = fmaf(aq.x, e1[0], v1);
                v0 = fmaf(aq.y, e0[1], v0); v1 = fmaf(aq.y, e1[1], v1);
                v0 = fmaf(aq.z, e0[2], v0); v1 = fmaf(aq.z, e1[2], v1);
                v0 = fmaf(aq.w, e0[3], v0); v1 = fmaf(aq.w, e1[3], v1);
                *(unsigned*)&sM[i][c2] = pack2(v0, v1);
            }
        }
        __syncthreads();   // A: m1 visible to MFMA
        v4f acc[8];
        // ---- L1 MM1 ----
        #pragma unroll
        for (int nt = 0; nt < 8; ++nt) acc[nt] = (v4f){0.f, 0.f, 0.f, 0.f};
        #pragma unroll
        for (int kk = 0; kk < 4; ++kk) {
            v8s a = *(const v8s*)&sM[wave * 16 + l16][kk * 32 + quad * 8];
            #pragma unroll
            for (int nt = 0; nt < 8; ++nt) {
                v8s b = *(const v8s*)(W1a + (nt * 16 + l16) * 128 + kk * 32 + quad * 8);
                acc[nt] = MFMA(a, b, acc[nt]);
            }
        }
        #pragma unroll
        for (int nt = 0; nt < 8; ++nt) {
            float bb = sPar[0][nt * 16 + l16];
            #pragma unroll
            for (int r = 0; r < 4; ++r)
                sM[wave * 16 + quad * 4 + r][nt * 16 + l16] = f2s(fmaxf(acc[nt][r] + bb, 0.f));
        }
        // ---- L1 MM2 (wave-private rows, no barrier) ----
        #pragma unroll
        for (int nt = 0; nt < 8; ++nt) acc[nt] = (v4f){0.f, 0.f, 0.f, 0.f};
        #pragma unroll
        for (int kk = 0; kk < 4; ++kk) {
            v8s a = *(const v8s*)&sM[wave * 16 + l16][kk * 32 + quad * 8];
            #pragma unroll
            for (int nt = 0; nt < 8; ++nt) {
                v8s b = *(const v8s*)(W2a + (nt * 16 + l16) * 128 + kk * 32 + quad * 8);
                acc[nt] = MFMA(a, b, acc[nt]);
            }
        }
        // ---- epi-1: bias, LN, relu, + z1 residual -> sZ ----
        #pragma unroll
        for (int r = 0; r < 4; ++r) {
            float s = 0.f, q = 0.f;
            #pragma unroll
            for (int nt = 0; nt < 8; ++nt) {
                float u = acc[nt][r] + sPar[1][nt * 16 + l16];
                acc[nt][r] = u; s += u; q += u * u;
            }
            #pragma unroll
            for (int d = 1; d < 16; d <<= 1) { s += __shfl_xor(s, d); q += __shfl_xor(q, d); }
            float mn = s * (1.f / 128.f);
            float rs = rsqrtf(q * (1.f / 128.f) - mn * mn + 1e-5f);
            int row = wave * 16 + quad * 4 + r;
            int pos = sPos[row];
            int pc = sPerm[(pos < 0 ? 0 : pos) * 6 + p];
            #pragma unroll
            for (int nt = 0; nt < 8; ++nt) {
                int col = nt * 16 + l16;
                float v = fmaxf((acc[nt][r] - mn) * rs * sPar[2][col] + sPar[3][col], 0.f);
                float self = (pos < 0) ? 1.f : (sEm[pc][col] + 1.f);
                sZ[row][col] = f2s(v + self);
            }
        }
        __syncthreads();   // B: sZ complete before gather
        // ---- gather from sZ -> sM ----
        {
            float a[32];
            #pragma unroll
            for (int u = 0; u < 32; ++u) a[u] = 0.f;
            for (int c = 0; c < gcnt; ++c) {
                const short* zr = &sZ[gnb[c]][cq];
                #pragma unroll
                for (int v = 0; v < 4; ++v) {
                    v8s z8 = *(const v8s*)(zr + v * 8);
                    #pragma unroll
                    for (int u = 0; u < 8; ++u) a[v * 8 + u] += s2f(z8[u]);
                }
            }
            #pragma unroll
            for (int v = 0; v < 4; ++v) {
                v8s o;
                #pragma unroll
                for (int u = 0; u < 8; ++u) o[u] = f2s(a[v * 8 + u]);
                *(v8s*)&sM[gnode][cq + v * 8] = o;
            }
        }
        __syncthreads();   // C: gather visible to MFMA
        // ---- L2 MM1 ----
        #pragma unroll
        for (int nt = 0; nt < 8; ++nt) acc[nt] = (v4f){0.f, 0.f, 0.f, 0.f};
        #pragma unroll
        for (int kk = 0; kk < 4; ++kk) {
            v8s a = *(const v8s*)&sM[wave * 16 + l16][kk * 32 + quad * 8];
            #pragma unroll
            for (int nt = 0; nt < 8; ++nt) {
                v8s b = *(const v8s*)(W1b + (nt * 16 + l16) * 128 + kk * 32 + quad * 8);
                acc[nt] = MFMA(a, b, acc[nt]);
            }
        }
        #pragma unroll
        for (int nt = 0; nt < 8; ++nt) {
            float bb = sPar[4][nt * 16 + l16];
            #pragma unroll
            for (int r = 0; r < 4; ++r)
                sM[wave * 16 + quad * 4 + r][nt * 16 + l16] = f2s(fmaxf(acc[nt][r] + bb, 0.f));
        }
        // ---- L2 MM2 ----
        #pragma unroll
        for (int nt = 0; nt < 8; ++nt) acc[nt] = (v4f){0.f, 0.f, 0.f, 0.f};
        #pragma unroll
        for (int kk = 0; kk < 4; ++kk) {
            v8s a = *(const v8s*)&sM[wave * 16 + l16][kk * 32 + quad * 8];
            #pragma unroll
            for (int nt = 0; nt < 8; ++nt) {
                v8s b = *(const v8s*)(W2b + (nt * 16 + l16) * 128 + kk * 32 + quad * 8);
                acc[nt] = MFMA(a, b, acc[nt]);
            }
        }
        // ---- epi-2: bias, LN, relu, + sZ residual -> meanAcc ----
        #pragma unroll
        for (int r = 0; r < 4; ++r) {
            float s = 0.f, q = 0.f;
            #pragma unroll
            for (int nt = 0; nt < 8; ++nt) {
                float u = acc[nt][r] + sPar[5][nt * 16 + l16];
                acc[nt][r] = u; s += u; q += u * u;
            }
            #pragma unroll
            for (int d = 1; d < 16; d <<= 1) { s += __shfl_xor(s, d); q += __shfl_xor(q, d); }
            float mn = s * (1.f / 128.f);
            float rs = rsqrtf(q * (1.f / 128.f) - mn * mn + 1e-5f);
            int row = wave * 16 + quad * 4 + r;
            #pragma unroll
            for (int nt = 0; nt < 8; ++nt) {
                int col = nt * 16 + l16;
                float v = fmaxf((acc[nt][r] - mn) * rs * sPar[6][col] + sPar[7][col], 0.f);
                v += s2f(sZ[row][col]);
                meanAcc[nt][r] += v;
            }
        }
        __syncthreads();   // D: sZ/sM free for next p
    }
    // ---- write zm: mean/6, masked, staged through sM for coalesced stores ----
    #pragma unroll
    for (int r = 0; r < 4; ++r) {
        int row = wave * 16 + quad * 4 + r;
        bool nul = (row >= nn);
        #pragma unroll
        for (int nt = 0; nt < 8; ++nt)
            sM[row][nt * 16 + l16] = f2s(nul ? 0.f : meanAcc[nt][r] * (1.f / 6.f));
    }
    __syncthreads();
    #pragma unroll
    for (int it = 0; it < 4; ++it) {
        int idx = it * 512 + t;
        int row = idx >> 4, c8 = idx & 15;
        *(v8s*)(zm + ((size_t)(b_s * 128 + row)) * 128 + c8 * 8) = *(const v8s*)&sM[row][c8 * 8];
    }
}

// ---------------- MP layer: gather + MFMA MLP + LN + residual (g and gl layers) --------
__global__ __launch_bounds__(256) void k_mp(
    const float* __restrict__ hsA, float* __restrict__ hsB,
    const unsigned char* __restrict__ nbr, const int* __restrict__ deg,
    const bf16* __restrict__ W1t, const float* __restrict__ b1,
    const bf16* __restrict__ W2t, const float* __restrict__ b2,
    const float* __restrict__ gam, const float* __restrict__ bet, int shift)
{
    __shared__ __align__(16) short smem[4][16][136];
    const int t = threadIdx.x, lane = t & 63, wave = t >> 6;
    const int quad = lane >> 4, l16 = lane & 15;
    const int b_s = blockIdx.x >> 1;
    const int node0 = (blockIdx.x & 1) * 64;
    const int g = b_s >> shift;
    const float* hblk = hsA + (size_t)b_s * 128 * 128;
    {
        const float* hp = hblk + lane * 2;
        for (int r = 0; r < 16; ++r) {
            int gi = g * 128 + node0 + wave * 16 + r;
            int cnt = deg[gi];
            const unsigned char* nb = nbr + (size_t)gi * NBR_CAP;
            float a0 = 0.f, a1 = 0.f;
            for (int c = 0; c < cnt; ++c) {
                const float* qp = hp + (int)nb[c] * 128;
                a0 += qp[0]; a1 += qp[1];
            }
            *(unsigned*)&smem[wave][r][lane * 2] = pack2(a0, a1);
        }
    }
    v4f acc[8];
    #pragma unroll
    for (int nt = 0; nt < 8; ++nt) acc[nt] = (v4f){0.f,0.f,0.f,0.f};
    #pragma unroll
    for (int kk = 0; kk < 4; ++kk) {
        v8s a = *(const v8s*)&smem[wave][l16][kk*32 + quad*8];
        #pragma unroll
        for (int nt = 0; nt < 8; ++nt) {
            v8s b = *(const v8s*)(W1t + (nt*16 + l16)*128 + kk*32 + quad*8);
            acc[nt] = MFMA(a, b, acc[nt]);
        }
    }
    #pragma unroll
    for (int nt = 0; nt < 8; ++nt) {
        float bb = b1[nt*16 + l16];
        #pragma unroll
        for (int r = 0; r < 4; ++r)
            smem[wave][quad*4 + r][nt*16 + l16] = f2s(fmaxf(acc[nt][r] + bb, 0.f));
    }
    #pragma unroll
    for (int nt = 0; nt < 8; ++nt) acc[nt] = (v4f){0.f,0.f,0.f,0.f};
    #pragma unroll
    for (int kk = 0; kk < 4; ++kk) {
        v8s a = *(const v8s*)&smem[wave][l16][kk*32 + quad*8];
        #pragma unroll
        for (int nt = 0; nt < 8; ++nt) {
            v8s b = *(const v8s*)(W2t + (nt*16 + l16)*128 + kk*32 + quad*8);
            acc[nt] = MFMA(a, b, acc[nt]);
        }
    }
    float bb2[8], gv[8], bv[8];
    #pragma unroll
    for (int nt = 0; nt < 8; ++nt) {
        int n = nt*16 + l16;
        bb2[nt] = b2[n]; gv[nt] = gam[n]; bv[nt] = bet[n];
    }
    #pragma unroll
    for (int r = 0; r < 4; ++r) {
        float s = 0.f, q = 0.f;
        #pragma unroll
        for (int nt = 0; nt < 8; ++nt) {
            float u = acc[nt][r] + bb2[nt];
            acc[nt][r] = u; s += u; q += u*u;
        }
        #pragma unroll
        for (int d = 1; d < 16; d <<= 1) { s += __shfl_xor(s, d); q += __shfl_xor(q, d); }
        float mn = s * (1.f/128.f);
        float rs = rsqrtf(q * (1.f/128.f) - mn*mn + 1e-5f);
        size_t gr = ((size_t)b_s * 128 + node0 + wave*16 + quad*4 + r) * 128;
        #pragma unroll
        for (int nt = 0; nt < 8; ++nt) {
            int col = nt*16 + l16;
            float v = fmaxf((acc[nt][r] - mn)*rs*gv[nt] + bv[nt], 0.f);
            hsB[gr + col] = v + hsA[gr + col];
        }
    }
}

// ---------------- hs.sum(axis=1) ----------------
__global__ __launch_bounds__(128) void k_hssum(const float* __restrict__ hs, float* __restrict__ hsum)
{
    const int b_s = blockIdx.x, hd = threadIdx.x;
    float v = 0.f;
    const float* r = hs + (size_t)b_s * 128 * H_ + hd;
    for (int i = 0; i < 128; ++i) v += r[(size_t)i * H_];
    hsum[(size_t)b_s * H_ + hd] = v;
}

// ---------------- segment max over 16 subgraphs per graph ----------------
__global__ __launch_bounds__(128) void k_maxpool(const float* __restrict__ hs2, float* __restrict__ pooled)
{
    const int g = blockIdx.x, hd = threadIdx.x;
    float m = -INFINITY;
    for (int s = 0; s < 16; ++s) m = fmaxf(m, hs2[((size_t)(g * 16 + s)) * H_ + hd]);
    pooled[(size_t)g * H_ + hd] = m;
}

// ---------------- final projection ----------------
__global__ __launch_bounds__(128) void k_out(const float* __restrict__ pooled2,
    const float* __restrict__ out_W, const float* __restrict__ out_b, float* __restrict__ out)
{
    __shared__ float red[128];
    const int g = blockIdx.x, hd = threadIdx.x;
    red[hd] = pooled2[(size_t)g * H_ + hd] * out_W[hd];
    __syncthreads();
    for (int s = 64; s > 0; s >>= 1) {
        if (hd < s) red[hd] += red[hd + s];
        __syncthreads();
    }
    if (hd == 0) out[g] = red[0] + out_b[0];
}

extern "C" void kernel_launch(void* const* d_in, const int* in_sizes, int n_in,
                              void* d_out, int out_size, void* d_ws, size_t ws_size,
                              hipStream_t stream)
{
    (void)in_sizes; (void)n_in; (void)out_size; (void)ws_size;
    const float* x     = (const float*)d_in[0];
    const float* adj   = (const float*)d_in[1];
    const float* idemb = (const float*)d_in[2];
    const float* in_W1 = (const float*)d_in[3];
    const float* in_b1 = (const float*)d_in[4];
    const float* in_W2 = (const float*)d_in[5];
    const float* in_b2 = (const float*)d_in[6];
    const float* in_g  = (const float*)d_in[7];
    const float* in_bn = (const float*)d_in[8];
    const float* gW1   = (const float*)d_in[9];
    const float* gb1   = (const float*)d_in[10];
    const float* gW2   = (const float*)d_in[11];
    const float* gb2   = (const float*)d_in[12];
    const float* gg    = (const float*)d_in[13];
    const float* gbn   = (const float*)d_in[14];
    const float* iW1   = (const float*)d_in[15];
    const float* ib1   = (const float*)d_in[16];
    const float* iW2   = (const float*)d_in[17];
    const float* ib2   = (const float*)d_in[18];
    const float* ig    = (const float*)d_in[19];
    const float* ibn   = (const float*)d_in[20];
    const float* glW1  = (const float*)d_in[21];
    const float* glb1  = (const float*)d_in[22];
    const float* glW2  = (const float*)d_in[23];
    const float* glb2  = (const float*)d_in[24];
    const float* glg   = (const float*)d_in[25];
    const float* glbn  = (const float*)d_in[26];
    const float* s1_W  = (const float*)d_in[27];
    const float* s1_b  = (const float*)d_in[28];
    const float* s2_W  = (const float*)d_in[29];
    const float* s2_b  = (const float*)d_in[30];
    const float* rW1   = (const float*)d_in[31];
    const float* rb1   = (const float*)d_in[32];
    const float* rW2   = (const float*)d_in[33];
    const float* rb2   = (const float*)d_in[34];
    const float* rg    = (const float*)d_in[35];
    const float* rbn   = (const float*)d_in[36];
    const float* out_W = (const float*)d_in[37];
    const float* out_b = (const float*)d_in[38];
    const int* subgs   = (const int*)d_in[39];
    const int* num_node= (const int*)d_in[41];
    const int* allperm = (const int*)d_in[42];

    // ---- workspace layout (peak ~90 MB) ----
    char* w = (char*)d_ws;
    float* hsA    = (float*)(w);                                // (512,128,128) f32 33.5 MB
    float* hsB    = (float*)(w + 33554432ull);                  // (512,128,128) f32 33.5 MB
    bf16*  zm     = (bf16*)(w + 67108864ull);                   // (512,128,128) bf16 16.8 MB
    bf16*  WT     = (bf16*)(w + 83886080ull);                   // 15 x (128x128) bf16
    char*  wc     = w + 83886080ull + 524288ull;
    float* hb     = (float*)(wc);                               // h ping (32,128,128) f32 2 MB
    float* hb2    = (float*)(wc + 2097152ull);                  // h pong / t1 scratch  2 MB
    float* hsum   = (float*)(wc + 4194304ull);                  // (512,128)
    float* hs2    = (float*)(wc + 4456448ull);                  // (512,128)
    float* pooled = (float*)(wc + 4718592ull);                  // (32,128)
    float* pooled2= (float*)(wc + 4734976ull);                  // (32,128)
    unsigned char* nbr = (unsigned char*)(wc + 4751360ull);     // 4096*48 u8
    int*   deg    = (int*)(wc + 4947968ull);                    // 4096 i32
    float* degf   = (float*)(wc + 4964352ull);                  // 4096 f32
    float* outp   = (float*)d_out;

    // prep: CSR + transposed bf16 weights
    k_csr<<<32, 128, 0, stream>>>(adj, nbr, deg, degf);
    k_wt<<<1920, 128, 0, stream>>>(in_W2, gW1, gW2, iW1, iW2, glW1, glW2, WT);

    // input embedding block: h = block(x) -> hb
    k_in_t1<<<4096, 128, 0, stream>>>(x, in_W1, in_b1, hb2);
    k_block<false, false><<<256, 128, 0, stream>>>(hb2, nullptr, hb,
        nullptr, nullptr, in_W2, in_b2, in_g, in_bn);

    // graph MP (3 layers), MFMA, ping-pong hb <-> hb2 (final in hb2)
    k_mp<<<64, 256, 0, stream>>>(hb, hb2, nbr, deg,
        WT + (size_t)1 * 16384, gb1, WT + (size_t)2 * 16384, gb2, gg, gbn, 0);
    k_mp<<<64, 256, 0, stream>>>(hb2, hb, nbr, deg,
        WT + (size_t)3 * 16384, gb1 + 128, WT + (size_t)4 * 16384, gb2 + 128, gg + 128, gbn + 128, 0);
    k_mp<<<64, 256, 0, stream>>>(hb, hb2, nbr, deg,
        WT + (size_t)5 * 16384, gb1 + 256, WT + (size_t)6 * 16384, gb2 + 256, gg + 256, gbn + 256, 0);

    // fused ID pipeline (both layers + p-mean) -> zm
    k_id12<<<512, 512, 0, stream>>>(adj, degf, subgs, allperm, idemb,
        nbr, deg, num_node, zm, WT, ib1, ib2, ig, ibn);

    // setmlp1 with gathered residual h[subgbatch] -> hsA
    k_gemm_relu<true, bf16><<<4096, 128, 0, stream>>>(zm, hb2, hsA, s1_W, s1_b);

    // global MP on subgraph copies (2 layers), ping-pong hsA/hsB
    k_mp<<<1024, 256, 0, stream>>>(hsA, hsB, nbr, deg,
        WT + (size_t)11 * 16384, glb1, WT + (size_t)12 * 16384, glb2, glg, glbn, 4);
    k_mp<<<1024, 256, 0, stream>>>(hsB, hsA, nbr, deg,
        WT + (size_t)13 * 16384, glb1 + 128, WT + (size_t)14 * 16384, glb2 + 128, glg + 128, glbn + 128, 4);

    // node sum -> setmlp2 -> segment max -> setmlp3 block -> output proj
    k_hssum<<<512, 128, 0, stream>>>(hsA, hsum);
    k_gemm_relu<false, float><<<32, 128, 0, stream>>>(hsum, nullptr, hs2, s2_W, s2_b);
    k_maxpool<<<32, 128, 0, stream>>>(hs2, pooled);
    k_block<true, true><<<2, 128, 0, stream>>>(pooled, pooled, pooled2,
        rW1, rb1, rW2, rb2, rg, rbn);
    k_out<<<32, 128, 0, stream>>>(pooled2, out_W, out_b, outp);
}

// Round 7
// 1190.914 us; speedup vs baseline: 1.3231x; 1.3231x over previous
//
#include <hip/hip_runtime.h>
#include <hip/hip_bf16.h>
#include <string.h>

typedef __hip_bfloat16 bf16;
typedef short v8s __attribute__((ext_vector_type(8)));
typedef float v4f __attribute__((ext_vector_type(4)));

#define H_ 128
#define P_ 6
#define K_ 4
#define NBR_CAP 48

__device__ __forceinline__ float ldf(const float* p, size_t i) { return p[i]; }
__device__ __forceinline__ float ldf(const bf16* p, size_t i) { return __bfloat162float(p[i]); }

__device__ __forceinline__ float s2f(short s) {
    unsigned int u = ((unsigned int)(unsigned short)s) << 16;
    float f; __builtin_memcpy(&f, &u, 4); return f;
}
__device__ __forceinline__ short f2s(float v) {
    bf16 h = __float2bfloat16(v);
    short s; __builtin_memcpy(&s, &h, 2); return s;
}
__device__ __forceinline__ unsigned pack2(float a0, float a1) {
    return ((unsigned)(unsigned short)f2s(a1) << 16) | (unsigned)(unsigned short)f2s(a0);
}
__device__ __forceinline__ v4f MFMA(v8s a, v8s b, v4f c) {
    return __builtin_amdgcn_mfma_f32_16x16x32_bf16(a, b, c, 0, 0, 0);
}

// ---------------- CSR build (parallel, ballot-ranked): 1 block per row ----------------
__global__ __launch_bounds__(128) void k_csr(const float* __restrict__ adj,
    unsigned char* __restrict__ nbr, int* __restrict__ deg, float* __restrict__ degf)
{
    __shared__ unsigned long long sm[2];
    __shared__ float ssum[2];
    const int row = blockIdx.x;                 // 4096 rows
    const int j = threadIdx.x;
    const int wv = j >> 6, ln = j & 63;
    float a = adj[(size_t)row * 128 + j];
    bool nz = (a != 0.f);
    unsigned long long m = __ballot(nz);
    float s = a;
    #pragma unroll
    for (int d = 1; d < 64; d <<= 1) s += __shfl_xor(s, d);
    if (ln == 0) { sm[wv] = m; ssum[wv] = s; }
    __syncthreads();
    if (nz) {
        unsigned long long below = (ln == 0) ? 0ull : (m & ((1ull << ln) - 1ull));
        int rank = __popcll(below) + (wv ? __popcll(sm[0]) : 0);
        if (rank < NBR_CAP) nbr[(size_t)row * NBR_CAP + rank] = (unsigned char)j;
    }
    if (j == 0) {
        int c = __popcll(sm[0]) + __popcll(sm[1]);
        deg[row] = (c < NBR_CAP) ? c : NBR_CAP;
        degf[row] = ssum[0] + ssum[1];
    }
}

// ---------------- transpose 16 (128x128) weights to bf16 WT[w][n][k] ----------------
// 0: in_W2 | 1..6: gW1/gW2 | 7..10: iW1/iW2 | 11..14: glW1/glW2 | 15: s1_W
__global__ __launch_bounds__(128) void k_wt(
    const float* in_W2, const float* gW1, const float* gW2,
    const float* iW1, const float* iW2, const float* glW1, const float* glW2,
    const float* s1_W, bf16* __restrict__ dst)
{
    const int w = blockIdx.x >> 7, n = blockIdx.x & 127, k = threadIdx.x;
    const float* s;
    switch (w) {
        case 0:  s = in_W2; break;
        case 1:  s = gW1; break;           case 2:  s = gW2; break;
        case 3:  s = gW1 + 16384; break;   case 4:  s = gW2 + 16384; break;
        case 5:  s = gW1 + 32768; break;   case 6:  s = gW2 + 32768; break;
        case 7:  s = iW1; break;           case 8:  s = iW2; break;
        case 9:  s = iW1 + 16384; break;   case 10: s = iW2 + 16384; break;
        case 11: s = glW1; break;          case 12: s = glW2; break;
        case 13: s = glW1 + 16384; break;  case 14: s = glW2 + 16384; break;
        default: s = s1_W; break;
    }
    dst[(size_t)w * 16384 + n * 128 + k] = __float2bfloat16(s[k * 128 + n]);
}

// ---------------- input embedding: t1 = relu(x * W1 + b1) ----------------
__global__ __launch_bounds__(128) void k_in_t1(const float* __restrict__ x,
    const float* __restrict__ W1, const float* __restrict__ b1, float* __restrict__ t1)
{
    int r = blockIdx.x, hd = threadIdx.x;
    t1[(size_t)r * H_ + hd] = fmaxf(fmaf(x[r], W1[hd], b1[hd]), 0.f);
}

// ---------------- generic VALU fused block (embedding + tiny tail only) ----------------
template<bool DO_MM1, bool HAS_RES>
__global__ __launch_bounds__(128) void k_block(
    const float* __restrict__ in, const float* __restrict__ res, float* __restrict__ out,
    const float* __restrict__ W1, const float* __restrict__ b1,
    const float* __restrict__ W2, const float* __restrict__ b2,
    const float* __restrict__ gam, const float* __restrict__ bet)
{
    __shared__ float sA[16][136];
    __shared__ float sB[16][136];
    __shared__ float sStat[32];
    const int hd = threadIdx.x;
    const size_t row0 = (size_t)blockIdx.x * 16;
    #pragma unroll
    for (int r = 0; r < 16; ++r) sA[r][hd] = in[(row0 + r) * H_ + hd];
    __syncthreads();
    float acc[16];
    if (DO_MM1) {
        #pragma unroll
        for (int r = 0; r < 16; ++r) acc[r] = b1[hd];
        for (int k = 0; k < H_; k += 4) {
            float w0 = W1[(k+0)*H_+hd], w1 = W1[(k+1)*H_+hd], w2 = W1[(k+2)*H_+hd], w3 = W1[(k+3)*H_+hd];
            #pragma unroll
            for (int r = 0; r < 16; ++r) {
                float4 a = *(const float4*)&sA[r][k];
                acc[r] = fmaf(a.x, w0, acc[r]); acc[r] = fmaf(a.y, w1, acc[r]);
                acc[r] = fmaf(a.z, w2, acc[r]); acc[r] = fmaf(a.w, w3, acc[r]);
            }
        }
        #pragma unroll
        for (int r = 0; r < 16; ++r) sB[r][hd] = fmaxf(acc[r], 0.f);
    } else {
        #pragma unroll
        for (int r = 0; r < 16; ++r) sB[r][hd] = sA[r][hd];
    }
    __syncthreads();
    #pragma unroll
    for (int r = 0; r < 16; ++r) acc[r] = b2[hd];
    for (int k = 0; k < H_; k += 4) {
        float w0 = W2[(k+0)*H_+hd], w1 = W2[(k+1)*H_+hd], w2 = W2[(k+2)*H_+hd], w3 = W2[(k+3)*H_+hd];
        #pragma unroll
        for (int r = 0; r < 16; ++r) {
            float4 a = *(const float4*)&sB[r][k];
            acc[r] = fmaf(a.x, w0, acc[r]); acc[r] = fmaf(a.y, w1, acc[r]);
            acc[r] = fmaf(a.z, w2, acc[r]); acc[r] = fmaf(a.w, w3, acc[r]);
        }
    }
    __syncthreads();
    #pragma unroll
    for (int r = 0; r < 16; ++r) sA[r][hd] = acc[r];
    __syncthreads();
    if (hd < 16) {
        float s = 0.f, ss = 0.f;
        for (int k = 0; k < H_; ++k) { float v = sA[hd][k]; s += v; ss += v * v; }
        float mean = s * (1.f / H_);
        float var = ss * (1.f / H_) - mean * mean;
        sStat[hd] = mean; sStat[16 + hd] = rsqrtf(var + 1e-5f);
    }
    __syncthreads();
    float gv = gam[hd], bv = bet[hd];
    #pragma unroll
    for (int r = 0; r < 16; ++r) {
        float v = fmaxf((acc[r] - sStat[r]) * sStat[16 + r] * gv + bv, 0.f);
        if (HAS_RES) v += res[(row0 + r) * H_ + hd];
        out[(row0 + r) * H_ + hd] = v;
    }
}

// ---------------- gemm + bias + relu (small tail: setmlp2) ----------------
template<bool GATHER, typename T>
__global__ __launch_bounds__(128) void k_gemm_relu(
    const T* __restrict__ in, const float* __restrict__ res, float* __restrict__ out,
    const float* __restrict__ W, const float* __restrict__ b)
{
    __shared__ float sA[16][136];
    const int hd = threadIdx.x;
    const size_t row0 = (size_t)blockIdx.x * 16;
    #pragma unroll
    for (int r = 0; r < 16; ++r) sA[r][hd] = ldf(in, (row0 + r) * H_ + hd);
    __syncthreads();
    float acc[16];
    #pragma unroll
    for (int r = 0; r < 16; ++r) acc[r] = b[hd];
    for (int k = 0; k < H_; k += 4) {
        float w0 = W[(k+0)*H_+hd], w1 = W[(k+1)*H_+hd], w2 = W[(k+2)*H_+hd], w3 = W[(k+3)*H_+hd];
        #pragma unroll
        for (int r = 0; r < 16; ++r) {
            float4 a = *(const float4*)&sA[r][k];
            acc[r] = fmaf(a.x, w0, acc[r]); acc[r] = fmaf(a.y, w1, acc[r]);
            acc[r] = fmaf(a.z, w2, acc[r]); acc[r] = fmaf(a.w, w3, acc[r]);
        }
    }
    #pragma unroll
    for (int r = 0; r < 16; ++r) {
        size_t rr = row0 + r;
        float v = fmaxf(acc[r], 0.f);
        if (GATHER) {
            int i = (int)(rr & 127);
            int g = (int)(rr >> 11);
            v += res[((size_t)(g * 128 + i)) * H_ + hd];
        }
        out[rr * H_ + hd] = v;
    }
}

// ---------------- FUSED ID PIPELINE: both ID layers + p-mean, one block/subgraph ----
// NOTE: no min-waves hint — R5/R6 proved __launch_bounds__(...,N) caps the unified
// VGPR+AGPR budget and forces catastrophic scratch spill (1.6 GB FETCH at R6).
__global__ __launch_bounds__(512) void k_id12(
    const float* __restrict__ adj, const float* __restrict__ degf,
    const int* __restrict__ subgs, const int* __restrict__ allperm,
    const float* __restrict__ idemb,
    const unsigned char* __restrict__ nbr, const int* __restrict__ deg,
    const int* __restrict__ num_node,
    bf16* __restrict__ zm, const bf16* __restrict__ WT,
    const float* __restrict__ ib1, const float* __restrict__ ib2,
    const float* __restrict__ ig, const float* __restrict__ ibn)
{
    __shared__ __align__(16) short sZ[128][136];
    __shared__ __align__(16) short sM[128][136];
    __shared__ float sEm[4][128];
    __shared__ float sAq[128][4];
    __shared__ float sDeg[128];
    __shared__ int   sPos[128];
    __shared__ int   sPerm[24];
    __shared__ float sPar[8][128];   // 0..3: L1 b1,b2,g,bn ; 4..7: L2
    const int t = threadIdx.x;
    const int lane = t & 63, wave = t >> 6;          // 8 waves
    const int quad = lane >> 4, l16 = lane & 15;
    const int b_s = blockIdx.x, g = b_s >> 4;
    const int nn = num_node[g];
    // ---- setup ----
    if (t < 24) sPerm[t] = allperm[t];
    {
        int row = t >> 7, col = t & 127;
        sEm[row][col] = idemb[row * 128 + col] - 1.f;
    }
    if (t < 128) {
        sDeg[t] = degf[g * 128 + t];
        int pos = -1;
        #pragma unroll
        for (int q = 0; q < 4; ++q) if (subgs[b_s * 4 + q] == t) pos = q;
        sPos[t] = pos;
    }
    {
        int i = t >> 2, q = t & 3;
        sAq[i][q] = adj[((size_t)(g * 128 + i)) * 128 + subgs[b_s * 4 + q]];
    }
    {
        int pi = t >> 7, c = t & 127;
        const float* p0 = (pi == 0) ? ib1 : (pi == 1) ? ib2 : (pi == 2) ? ig : ibn;
        sPar[pi][c] = p0[c];
        sPar[pi + 4][c] = p0[c + 128];
    }
    // gather assignment: 8 threads/node, 16 cols each, 2 passes of 64 nodes
    const int gn8 = t >> 3;                     // 0..63
    const int cq16 = (t & 7) * 16;
    const int cnt0 = deg[g * 128 + gn8];
    const int cnt1 = deg[g * 128 + 64 + gn8];
    const unsigned char* gnb0 = nbr + (size_t)(g * 128 + gn8) * NBR_CAP;
    const unsigned char* gnb1 = nbr + (size_t)(g * 128 + 64 + gn8) * NBR_CAP;
    __syncthreads();

    v4f meanAcc[8];
    #pragma unroll
    for (int nt = 0; nt < 8; ++nt) meanAcc[nt] = (v4f){0.f, 0.f, 0.f, 0.f};
    const bf16* W1a = WT + (size_t)7 * 16384;
    const bf16* W2a = WT + (size_t)8 * 16384;
    const bf16* W1b = WT + (size_t)9 * 16384;
    const bf16* W2b = WT + (size_t)10 * 16384;

    for (int p = 0; p < P_; ++p) {
        // ---- m1 closed-form -> sM ----
        {
            const int c2 = (t & 63) * 2, rq = t >> 6;
            float e0[4], e1[4];
            #pragma unroll
            for (int q = 0; q < 4; ++q) {
                int e = sPerm[q * 6 + p];
                e0[q] = sEm[e][c2]; e1[q] = sEm[e][c2 + 1];
            }
            #pragma unroll
            for (int r = 0; r < 16; ++r) {
                int i = rq * 16 + r;
                float4 aq = *(const float4*)&sAq[i][0];
                float dg = sDeg[i];
                float v0 = dg, v1 = dg;
                v0 = fmaf(aq.x, e0[0], v0); v1 = fmaf(aq.x, e1[0], v1);
                v0 = fmaf(aq.y, e0[1], v0); v1 = fmaf(aq.y, e1[1], v1);
                v0 = fmaf(aq.z, e0[2], v0); v1 = fmaf(aq.z, e1[2], v1);
                v0 = fmaf(aq.w, e0[3], v0); v1 = fmaf(aq.w, e1[3], v1);
                *(unsigned*)&sM[i][c2] = pack2(v0, v1);
            }
        }
        __syncthreads();   // A: m1 visible to MFMA
        v4f acc[8];
        // ---- L1 MM1 ----
        #pragma unroll
        for (int nt = 0; nt < 8; ++nt) acc[nt] = (v4f){0.f, 0.f, 0.f, 0.f};
        #pragma unroll
        for (int kk = 0; kk < 4; ++kk) {
            v8s a = *(const v8s*)&sM[wave * 16 + l16][kk * 32 + quad * 8];
            #pragma unroll
            for (int nt = 0; nt < 8; ++nt) {
                v8s b = *(const v8s*)(W1a + (nt * 16 + l16) * 128 + kk * 32 + quad * 8);
                acc[nt] = MFMA(a, b, acc[nt]);
            }
        }
        #pragma unroll
        for (int nt = 0; nt < 8; ++nt) {
            float bb = sPar[0][nt * 16 + l16];
            #pragma unroll
            for (int r = 0; r < 4; ++r)
                sM[wave * 16 + quad * 4 + r][nt * 16 + l16] = f2s(fmaxf(acc[nt][r] + bb, 0.f));
        }
        // ---- L1 MM2 (wave-private rows) ----
        #pragma unroll
        for (int nt = 0; nt < 8; ++nt) acc[nt] = (v4f){0.f, 0.f, 0.f, 0.f};
        #pragma unroll
        for (int kk = 0; kk < 4; ++kk) {
            v8s a = *(const v8s*)&sM[wave * 16 + l16][kk * 32 + quad * 8];
            #pragma unroll
            for (int nt = 0; nt < 8; ++nt) {
                v8s b = *(const v8s*)(W2a + (nt * 16 + l16) * 128 + kk * 32 + quad * 8);
                acc[nt] = MFMA(a, b, acc[nt]);
            }
        }
        // ---- epi-1: bias, LN, relu, + z1 residual -> sZ ----
        #pragma unroll
        for (int r = 0; r < 4; ++r) {
            float s = 0.f, q = 0.f;
            #pragma unroll
            for (int nt = 0; nt < 8; ++nt) {
                float u = acc[nt][r] + sPar[1][nt * 16 + l16];
                acc[nt][r] = u; s += u; q += u * u;
            }
            #pragma unroll
            for (int d = 1; d < 16; d <<= 1) { s += __shfl_xor(s, d); q += __shfl_xor(q, d); }
            float mn = s * (1.f / 128.f);
            float rs = rsqrtf(q * (1.f / 128.f) - mn * mn + 1e-5f);
            int row = wave * 16 + quad * 4 + r;
            int pos = sPos[row];
            int pc = sPerm[(pos < 0 ? 0 : pos) * 6 + p];
            #pragma unroll
            for (int nt = 0; nt < 8; ++nt) {
                int col = nt * 16 + l16;
                float v = fmaxf((acc[nt][r] - mn) * rs * sPar[2][col] + sPar[3][col], 0.f);
                float self = (pos < 0) ? 1.f : (sEm[pc][col] + 1.f);
                sZ[row][col] = f2s(v + self);
            }
        }
        __syncthreads();   // B: sZ complete before gather
        // ---- gather from sZ -> sM (8 thr/node, 16 cols, 2 passes) ----
        #pragma unroll
        for (int pass = 0; pass < 2; ++pass) {
            int node = pass * 64 + gn8;
            int cnt = pass ? cnt1 : cnt0;
            const unsigned char* nb = pass ? gnb1 : gnb0;
            float a[16];
            #pragma unroll
            for (int u = 0; u < 16; ++u) a[u] = 0.f;
            for (int c = 0; c < cnt; ++c) {
                const short* zr = &sZ[nb[c]][cq16];
                #pragma unroll
                for (int v = 0; v < 2; ++v) {
                    v8s z8 = *(const v8s*)(zr + v * 8);
                    #pragma unroll
                    for (int u = 0; u < 8; ++u) a[v * 8 + u] += s2f(z8[u]);
                }
            }
            #pragma unroll
            for (int v = 0; v < 2; ++v) {
                v8s o;
                #pragma unroll
                for (int u = 0; u < 8; ++u) o[u] = f2s(a[v * 8 + u]);
                *(v8s*)&sM[node][cq16 + v * 8] = o;
            }
        }
        __syncthreads();   // C: gather visible to MFMA
        // ---- L2 MM1 ----
        #pragma unroll
        for (int nt = 0; nt < 8; ++nt) acc[nt] = (v4f){0.f, 0.f, 0.f, 0.f};
        #pragma unroll
        for (int kk = 0; kk < 4; ++kk) {
            v8s a = *(const v8s*)&sM[wave * 16 + l16][kk * 32 + quad * 8];
            #pragma unroll
            for (int nt = 0; nt < 8; ++nt) {
                v8s b = *(const v8s*)(W1b + (nt * 16 + l16) * 128 + kk * 32 + quad * 8);
                acc[nt] = MFMA(a, b, acc[nt]);
            }
        }
        #pragma unroll
        for (int nt = 0; nt < 8; ++nt) {
            float bb = sPar[4][nt * 16 + l16];
            #pragma unroll
            for (int r = 0; r < 4; ++r)
                sM[wave * 16 + quad * 4 + r][nt * 16 + l16] = f2s(fmaxf(acc[nt][r] + bb, 0.f));
        }
        // ---- L2 MM2 ----
        #pragma unroll
        for (int nt = 0; nt < 8; ++nt) acc[nt] = (v4f){0.f, 0.f, 0.f, 0.f};
        #pragma unroll
        for (int kk = 0; kk < 4; ++kk) {
            v8s a = *(const v8s*)&sM[wave * 16 + l16][kk * 32 + quad * 8];
            #pragma unroll
            for (int nt = 0; nt < 8; ++nt) {
                v8s b = *(const v8s*)(W2b + (nt * 16 + l16) * 128 + kk * 32 + quad * 8);
                acc[nt] = MFMA(a, b, acc[nt]);
            }
        }
        // ---- epi-2: bias, LN, relu, + sZ residual -> meanAcc ----
        #pragma unroll
        for (int r = 0; r < 4; ++r) {
            float s = 0.f, q = 0.f;
            #pragma unroll
            for (int nt = 0; nt < 8; ++nt) {
                float u = acc[nt][r] + sPar[5][nt * 16 + l16];
                acc[nt][r] = u; s += u; q += u * u;
            }
            #pragma unroll
            for (int d = 1; d < 16; d <<= 1) { s += __shfl_xor(s, d); q += __shfl_xor(q, d); }
            float mn = s * (1.f / 128.f);
            float rs = rsqrtf(q * (1.f / 128.f) - mn * mn + 1e-5f);
            int row = wave * 16 + quad * 4 + r;
            #pragma unroll
            for (int nt = 0; nt < 8; ++nt) {
                int col = nt * 16 + l16;
                float v = fmaxf((acc[nt][r] - mn) * rs * sPar[6][col] + sPar[7][col], 0.f);
                v += s2f(sZ[row][col]);
                meanAcc[nt][r] += v;
            }
        }
        __syncthreads();   // D: sZ/sM free for next p
    }
    // ---- write zm: mean/6, masked, staged through sM for coalesced stores ----
    #pragma unroll
    for (int r = 0; r < 4; ++r) {
        int row = wave * 16 + quad * 4 + r;
        bool nul = (row >= nn);
        #pragma unroll
        for (int nt = 0; nt < 8; ++nt)
            sM[row][nt * 16 + l16] = f2s(nul ? 0.f : meanAcc[nt][r] * (1.f / 6.f));
    }
    __syncthreads();
    #pragma unroll
    for (int it = 0; it < 4; ++it) {
        int idx = it * 512 + t;
        int row = idx >> 4, c8 = idx & 15;
        *(v8s*)(zm + ((size_t)(b_s * 128 + row)) * 128 + c8 * 8) = *(const v8s*)&sM[row][c8 * 8];
    }
}

// ---------------- MP layer: gather + MFMA MLP + LN + residual (g and gl layers) --------
__global__ __launch_bounds__(256) void k_mp(
    const float* __restrict__ hsA, float* __restrict__ hsB,
    const unsigned char* __restrict__ nbr, const int* __restrict__ deg,
    const bf16* __restrict__ W1t, const float* __restrict__ b1,
    const bf16* __restrict__ W2t, const float* __restrict__ b2,
    const float* __restrict__ gam, const float* __restrict__ bet, int shift)
{
    __shared__ __align__(16) short smem[4][16][136];
    const int t = threadIdx.x, lane = t & 63, wave = t >> 6;
    const int quad = lane >> 4, l16 = lane & 15;
    const int b_s = blockIdx.x >> 1;
    const int node0 = (blockIdx.x & 1) * 64;
    const int g = b_s >> shift;
    const float* hblk = hsA + (size_t)b_s * 128 * 128;
    {
        const float* hp = hblk + lane * 2;
        for (int r = 0; r < 16; ++r) {
            int gi = g * 128 + node0 + wave * 16 + r;
            int cnt = deg[gi];
            const unsigned char* nb = nbr + (size_t)gi * NBR_CAP;
            float a0 = 0.f, a1 = 0.f;
            for (int c = 0; c < cnt; ++c) {
                const float* qp = hp + (int)nb[c] * 128;
                a0 += qp[0]; a1 += qp[1];
            }
            *(unsigned*)&smem[wave][r][lane * 2] = pack2(a0, a1);
        }
    }
    v4f acc[8];
    #pragma unroll
    for (int nt = 0; nt < 8; ++nt) acc[nt] = (v4f){0.f,0.f,0.f,0.f};
    #pragma unroll
    for (int kk = 0; kk < 4; ++kk) {
        v8s a = *(const v8s*)&smem[wave][l16][kk*32 + quad*8];
        #pragma unroll
        for (int nt = 0; nt < 8; ++nt) {
            v8s b = *(const v8s*)(W1t + (nt*16 + l16)*128 + kk*32 + quad*8);
            acc[nt] = MFMA(a, b, acc[nt]);
        }
    }
    #pragma unroll
    for (int nt = 0; nt < 8; ++nt) {
        float bb = b1[nt*16 + l16];
        #pragma unroll
        for (int r = 0; r < 4; ++r)
            smem[wave][quad*4 + r][nt*16 + l16] = f2s(fmaxf(acc[nt][r] + bb, 0.f));
    }
    #pragma unroll
    for (int nt = 0; nt < 8; ++nt) acc[nt] = (v4f){0.f,0.f,0.f,0.f};
    #pragma unroll
    for (int kk = 0; kk < 4; ++kk) {
        v8s a = *(const v8s*)&smem[wave][l16][kk*32 + quad*8];
        #pragma unroll
        for (int nt = 0; nt < 8; ++nt) {
            v8s b = *(const v8s*)(W2t + (nt*16 + l16)*128 + kk*32 + quad*8);
            acc[nt] = MFMA(a, b, acc[nt]);
        }
    }
    float bb2[8], gv[8], bv[8];
    #pragma unroll
    for (int nt = 0; nt < 8; ++nt) {
        int n = nt*16 + l16;
        bb2[nt] = b2[n]; gv[nt] = gam[n]; bv[nt] = bet[n];
    }
    #pragma unroll
    for (int r = 0; r < 4; ++r) {
        float s = 0.f, q = 0.f;
        #pragma unroll
        for (int nt = 0; nt < 8; ++nt) {
            float u = acc[nt][r] + bb2[nt];
            acc[nt][r] = u; s += u; q += u*u;
        }
        #pragma unroll
        for (int d = 1; d < 16; d <<= 1) { s += __shfl_xor(s, d); q += __shfl_xor(q, d); }
        float mn = s * (1.f/128.f);
        float rs = rsqrtf(q * (1.f/128.f) - mn*mn + 1e-5f);
        size_t gr = ((size_t)b_s * 128 + node0 + wave*16 + quad*4 + r) * 128;
        #pragma unroll
        for (int nt = 0; nt < 8; ++nt) {
            int col = nt*16 + l16;
            float v = fmaxf((acc[nt][r] - mn)*rs*gv[nt] + bv[nt], 0.f);
            hsB[gr + col] = v + hsA[gr + col];
        }
    }
}

// ---------------- setmlp1 (MFMA): hsA = relu(zm @ s1_W + b) + h[subgbatch] ----------------
__global__ __launch_bounds__(256) void k_s1(
    const bf16* __restrict__ zm, const float* __restrict__ h, float* __restrict__ hsA,
    const bf16* __restrict__ Wt, const float* __restrict__ b)
{
    __shared__ __align__(16) short sA[64][136];
    const int t = threadIdx.x, lane = t & 63, wave = t >> 6;
    const int quad = lane >> 4, l16 = lane & 15;
    const int b_s = blockIdx.x >> 1;
    const int node0 = (blockIdx.x & 1) * 64;
    const int g = b_s >> 4;
    #pragma unroll
    for (int it = 0; it < 4; ++it) {
        int idx = it * 256 + t;
        int row = idx >> 4, c8 = idx & 15;
        *(v8s*)&sA[row][c8 * 8] =
            *(const v8s*)(zm + ((size_t)(b_s * 128 + node0 + row)) * 128 + c8 * 8);
    }
    __syncthreads();
    v4f acc[8];
    #pragma unroll
    for (int nt = 0; nt < 8; ++nt) acc[nt] = (v4f){0.f,0.f,0.f,0.f};
    #pragma unroll
    for (int kk = 0; kk < 4; ++kk) {
        v8s a = *(const v8s*)&sA[wave * 16 + l16][kk*32 + quad*8];
        #pragma unroll
        for (int nt = 0; nt < 8; ++nt) {
            v8s bw = *(const v8s*)(Wt + (nt*16 + l16)*128 + kk*32 + quad*8);
            acc[nt] = MFMA(a, bw, acc[nt]);
        }
    }
    #pragma unroll
    for (int r = 0; r < 4; ++r) {
        int row = node0 + wave * 16 + quad * 4 + r;
        size_t ho = ((size_t)(g * 128 + row)) * 128;
        size_t go = ((size_t)(b_s * 128 + row)) * 128;
        #pragma unroll
        for (int nt = 0; nt < 8; ++nt) {
            int col = nt * 16 + l16;
            float v = fmaxf(acc[nt][r] + b[col], 0.f);
            hsA[go + col] = v + h[ho + col];
        }
    }
}

// ---------------- hs.sum(axis=1) ----------------
__global__ __launch_bounds__(128) void k_hssum(const float* __restrict__ hs, float* __restrict__ hsum)
{
    const int b_s = blockIdx.x, hd = threadIdx.x;
    float v = 0.f;
    const float* r = hs + (size_t)b_s * 128 * H_ + hd;
    for (int i = 0; i < 128; ++i) v += r[(size_t)i * H_];
    hsum[(size_t)b_s * H_ + hd] = v;
}

// ---------------- segment max over 16 subgraphs per graph ----------------
__global__ __launch_bounds__(128) void k_maxpool(const float* __restrict__ hs2, float* __restrict__ pooled)
{
    const int g = blockIdx.x, hd = threadIdx.x;
    float m = -INFINITY;
    for (int s = 0; s < 16; ++s) m = fmaxf(m, hs2[((size_t)(g * 16 + s)) * H_ + hd]);
    pooled[(size_t)g * H_ + hd] = m;
}

// ---------------- final projection ----------------
__global__ __launch_bounds__(128) void k_out(const float* __restrict__ pooled2,
    const float* __restrict__ out_W, const float* __restrict__ out_b, float* __restrict__ out)
{
    __shared__ float red[128];
    const int g = blockIdx.x, hd = threadIdx.x;
    red[hd] = pooled2[(size_t)g * H_ + hd] * out_W[hd];
    __syncthreads();
    for (int s = 64; s > 0; s >>= 1) {
        if (hd < s) red[hd] += red[hd + s];
        __syncthreads();
    }
    if (hd == 0) out[g] = red[0] + out_b[0];
}

extern "C" void kernel_launch(void* const* d_in, const int* in_sizes, int n_in,
                              void* d_out, int out_size, void* d_ws, size_t ws_size,
                              hipStream_t stream)
{
    (void)in_sizes; (void)n_in; (void)out_size; (void)ws_size;
    const float* x     = (const float*)d_in[0];
    const float* adj   = (const float*)d_in[1];
    const float* idemb = (const float*)d_in[2];
    const float* in_W1 = (const float*)d_in[3];
    const float* in_b1 = (const float*)d_in[4];
    const float* in_W2 = (const float*)d_in[5];
    const float* in_b2 = (const float*)d_in[6];
    const float* in_g  = (const float*)d_in[7];
    const float* in_bn = (const float*)d_in[8];
    const float* gW1   = (const float*)d_in[9];
    const float* gb1   = (const float*)d_in[10];
    const float* gW2   = (const float*)d_in[11];
    const float* gb2   = (const float*)d_in[12];
    const float* gg    = (const float*)d_in[13];
    const float* gbn   = (const float*)d_in[14];
    const float* iW1   = (const float*)d_in[15];
    const float* ib1   = (const float*)d_in[16];
    const float* iW2   = (const float*)d_in[17];
    const float* ib2   = (const float*)d_in[18];
    const float* ig    = (const float*)d_in[19];
    const float* ibn   = (const float*)d_in[20];
    const float* glW1  = (const float*)d_in[21];
    const float* glb1  = (const float*)d_in[22];
    const float* glW2  = (const float*)d_in[23];
    const float* glb2  = (const float*)d_in[24];
    const float* glg   = (const float*)d_in[25];
    const float* glbn  = (const float*)d_in[26];
    const float* s1_W  = (const float*)d_in[27];
    const float* s1_b  = (const float*)d_in[28];
    const float* s2_W  = (const float*)d_in[29];
    const float* s2_b  = (const float*)d_in[30];
    const float* rW1   = (const float*)d_in[31];
    const float* rb1   = (const float*)d_in[32];
    const float* rW2   = (const float*)d_in[33];
    const float* rb2   = (const float*)d_in[34];
    const float* rg    = (const float*)d_in[35];
    const float* rbn   = (const float*)d_in[36];
    const float* out_W = (const float*)d_in[37];
    const float* out_b = (const float*)d_in[38];
    const int* subgs   = (const int*)d_in[39];
    const int* num_node= (const int*)d_in[41];
    const int* allperm = (const int*)d_in[42];

    // ---- workspace layout (peak ~90 MB) ----
    char* w = (char*)d_ws;
    float* hsA    = (float*)(w);                                // (512,128,128) f32 33.5 MB
    float* hsB    = (float*)(w + 33554432ull);                  // (512,128,128) f32 33.5 MB
    bf16*  zm     = (bf16*)(w + 67108864ull);                   // (512,128,128) bf16 16.8 MB
    bf16*  WT     = (bf16*)(w + 83886080ull);                   // 16 x (128x128) bf16
    char*  wc     = w + 83886080ull + 524288ull;
    float* hb     = (float*)(wc);                               // h ping (32,128,128) f32 2 MB
    float* hb2    = (float*)(wc + 2097152ull);                  // h pong / t1 scratch  2 MB
    float* hsum   = (float*)(wc + 4194304ull);                  // (512,128)
    float* hs2    = (float*)(wc + 4456448ull);                  // (512,128)
    float* pooled = (float*)(wc + 4718592ull);                  // (32,128)
    float* pooled2= (float*)(wc + 4734976ull);                  // (32,128)
    unsigned char* nbr = (unsigned char*)(wc + 4751360ull);     // 4096*48 u8
    int*   deg    = (int*)(wc + 4947968ull);                    // 4096 i32
    float* degf   = (float*)(wc + 4964352ull);                  // 4096 f32
    float* outp   = (float*)d_out;

    // prep: CSR + transposed bf16 weights
    k_csr<<<4096, 128, 0, stream>>>(adj, nbr, deg, degf);
    k_wt<<<2048, 128, 0, stream>>>(in_W2, gW1, gW2, iW1, iW2, glW1, glW2, s1_W, WT);

    // input embedding block: h = block(x) -> hb
    k_in_t1<<<4096, 128, 0, stream>>>(x, in_W1, in_b1, hb2);
    k_block<false, false><<<256, 128, 0, stream>>>(hb2, nullptr, hb,
        nullptr, nullptr, in_W2, in_b2, in_g, in_bn);

    // graph MP (3 layers), MFMA, ping-pong hb <-> hb2 (final in hb2)
    k_mp<<<64, 256, 0, stream>>>(hb, hb2, nbr, deg,
        WT + (size_t)1 * 16384, gb1, WT + (size_t)2 * 16384, gb2, gg, gbn, 0);
    k_mp<<<64, 256, 0, stream>>>(hb2, hb, nbr, deg,
        WT + (size_t)3 * 16384, gb1 + 128, WT + (size_t)4 * 16384, gb2 + 128, gg + 128, gbn + 128, 0);
    k_mp<<<64, 256, 0, stream>>>(hb, hb2, nbr, deg,
        WT + (size_t)5 * 16384, gb1 + 256, WT + (size_t)6 * 16384, gb2 + 256, gg + 256, gbn + 256, 0);

    // fused ID pipeline (both layers + p-mean) -> zm
    k_id12<<<512, 512, 0, stream>>>(adj, degf, subgs, allperm, idemb,
        nbr, deg, num_node, zm, WT, ib1, ib2, ig, ibn);

    // setmlp1 (MFMA) with gathered residual h[subgbatch] -> hsA
    k_s1<<<1024, 256, 0, stream>>>(zm, hb2, hsA, WT + (size_t)15 * 16384, s1_b);

    // global MP on subgraph copies (2 layers), ping-pong hsA/hsB
    k_mp<<<1024, 256, 0, stream>>>(hsA, hsB, nbr, deg,
        WT + (size_t)11 * 16384, glb1, WT + (size_t)12 * 16384, glb2, glg, glbn, 4);
    k_mp<<<1024, 256, 0, stream>>>(hsB, hsA, nbr, deg,
        WT + (size_t)13 * 16384, glb1 + 128, WT + (size_t)14 * 16384, glb2 + 128, glg + 128, glbn + 128, 4);

    // node sum -> setmlp2 -> segment max -> setmlp3 block -> output proj
    k_hssum<<<512, 128, 0, stream>>>(hsA, hsum);
    k_gemm_relu<false, float><<<32, 128, 0, stream>>>(hsum, nullptr, hs2, s2_W, s2_b);
    k_maxpool<<<32, 128, 0, stream>>>(hs2, pooled);
    k_block<true, true><<<2, 128, 0, stream>>>(pooled, pooled, pooled2,
        rW1, rb1, rW2, rb2, rg, rbn);
    k_out<<<32, 128, 0, stream>>>(pooled2, out_W, out_b, outp);
}